// Round 6
// baseline (1553.171 us; speedup 1.0000x reference)
//
#include <hip/hip_runtime.h>

typedef __bf16 bf16;
typedef __attribute__((ext_vector_type(4))) float floatx4;
typedef __attribute__((ext_vector_type(8))) bf16 bf16x8;
typedef __attribute__((ext_vector_type(4))) bf16 bf16x4;
typedef __attribute__((ext_vector_type(4))) unsigned uintx4;
typedef __attribute__((ext_vector_type(2))) unsigned uintx2;

typedef const __attribute__((address_space(1))) void gconst_t;
typedef __attribute__((address_space(3))) void lds_t;

__device__ __forceinline__ void load_lds16(const void* g, void* l) {
  __builtin_amdgcn_global_load_lds((gconst_t*)g, (lds_t*)l, 16, 0, 0);
}

__device__ __forceinline__ float sigm(float x) { return 1.f / (1.f + __expf(-x)); }
__device__ __forceinline__ float tanh_f(float x) { return 2.f / (1.f + __expf(-2.f * x)) - 1.f; }

// --- device-coherent (cross-XCD) access helpers: bypass L1/L2 via sc0 sc1 ---
__device__ __forceinline__ void st_coh_u32(void* p, unsigned v) {
  asm volatile("global_store_dword %0, %1, off sc0 sc1" :: "v"(p), "v"(v) : "memory");
}
__device__ __forceinline__ void st_coh_u128(void* p, uintx4 v) {
  asm volatile("global_store_dwordx4 %0, %1, off sc0 sc1" :: "v"(p), "v"(v) : "memory");
}
__device__ __forceinline__ uintx2 ld_coh_u32x2(const void* p) {
  uintx2 r;
  asm volatile("global_load_dwordx2 %0, %1, off sc0 sc1\n\ts_waitcnt vmcnt(0)"
               : "=v"(r) : "v"(p) : "memory");
  return r;
}
__device__ __forceinline__ uintx4 ld_coh_u32x4(const void* p) {
  uintx4 r;
  asm volatile("global_load_dwordx4 %0, %1, off sc0 sc1\n\ts_waitcnt vmcnt(0)"
               : "=v"(r) : "v"(p) : "memory");
  return r;
}

// ---------------------------------------------------------------------------
// fp32 -> bf16 convert (vectorized x4)
// ---------------------------------------------------------------------------
__global__ void k_cvt(const float* __restrict__ in, bf16* __restrict__ out, int n4) {
  int i = blockIdx.x * 256 + threadIdx.x;
  if (i < n4) {
    float4 v = ((const float4*)in)[i];
    bf16x4 u = { (bf16)v.x, (bf16)v.y, (bf16)v.z, (bf16)v.w };
    ((bf16x4*)out)[i] = u;
  }
}

__global__ void k_bias_sum(const float* __restrict__ a, const float* __restrict__ b,
                           float* __restrict__ o, int n) {
  int i = blockIdx.x * 256 + threadIdx.x;
  if (i < n) o[i] = a[i] + b[i];
}

__global__ void k_zero(unsigned* __restrict__ p) {
  p[threadIdx.x] = 0u;   // 256 flag words (layer0: 0..127, layer1: 128..255)
}

// ---------------------------------------------------------------------------
// linear (32x2048 @ 2048x512^T) + batchnorm over batch dim -> xs row t=0 (bf16)
// ---------------------------------------------------------------------------
__global__ __launch_bounds__(256) void k_linbn(
    const float* __restrict__ img, const float* __restrict__ W,
    const float* __restrict__ lb, const float* __restrict__ gamma,
    const float* __restrict__ beta, bf16* __restrict__ xs)
{
  const int e = blockIdx.x;                 // 0..511
  const int wave = threadIdx.x >> 6, lane = threadIdx.x & 63;
  __shared__ float sums[32];
  const float* wrow = W + (size_t)e * 2048;
  for (int b = wave; b < 32; b += 4) {
    const float* irow = img + (size_t)b * 2048;
    float s = 0.f;
#pragma unroll
    for (int j = 0; j < 8; ++j) {
      const int k = j * 256 + lane * 4;
      float4 a = *(const float4*)(irow + k);
      float4 w = *(const float4*)(wrow + k);
      s += a.x * w.x + a.y * w.y + a.z * w.z + a.w * w.w;
    }
#pragma unroll
    for (int off = 32; off > 0; off >>= 1) s += __shfl_down(s, off);
    if (lane == 0) sums[b] = s + lb[e];
  }
  __syncthreads();
  if (threadIdx.x < 32) {
    const float x = sums[threadIdx.x];
    float m = x, m2 = x * x;
#pragma unroll
    for (int mask = 16; mask > 0; mask >>= 1) {
      m  += __shfl_xor(m, mask);
      m2 += __shfl_xor(m2, mask);
    }
    m *= (1.f / 32.f); m2 *= (1.f / 32.f);
    const float var = m2 - m * m;
    const float xn = gamma[e] * (x - m) * rsqrtf(var + 1e-5f) + beta[e];
    xs[(size_t)threadIdx.x * 64 * 512 + e] = (bf16)xn;  // row r = b*64 + 0
  }
}

// ---------------------------------------------------------------------------
// embedding gather -> xs rows t=1..63 (bf16)
// ---------------------------------------------------------------------------
__global__ void k_embed(const int* __restrict__ cap, const float* __restrict__ emb,
                        bf16* __restrict__ xs)
{
  const int blk = blockIdx.x;               // 0..2015
  const int b = blk / 63, j = blk % 63;     // t = j+1
  const int tok = cap[b * 64 + j];
  const float* src = emb + (size_t)tok * 512;
  bf16* dst = xs + ((size_t)b * 64 + j + 1) * 512;
  float4 v = ((const float4*)src)[threadIdx.x];
  bf16x4 u = { (bf16)v.x, (bf16)v.y, (bf16)v.z, (bf16)v.w };
  *(bf16x4*)(dst + threadIdx.x * 4) = u;
}

// ---------------------------------------------------------------------------
// GEMM: C[M,N] = A[M,K](bf16) @ Bt[N,K](fp32, cvt during staging)^T + bias.
// m97 structure + XCD-chunked swizzle. (fallback / small-GEMM path)
// ---------------------------------------------------------------------------
__global__ __launch_bounds__(256) void k_gemm(
    const bf16* __restrict__ A, const float* __restrict__ Bt,
    const float* __restrict__ bias, float* __restrict__ C,
    int K, int N)
{
  __shared__ bf16 lA[128 * 32];
  __shared__ bf16 lB[128 * 32];
  const int tid = threadIdx.x;
  const int lane = tid & 63;
  const int wm = ((tid >> 6) >> 1) * 64;
  const int wn = ((tid >> 6) & 1) * 64;
  const int nwg = gridDim.x * gridDim.y;
  int wg = blockIdx.y * gridDim.x + blockIdx.x;
  wg = (wg & 7) * (nwg >> 3) + (wg >> 3);        // XCD-chunked, bijective (nwg%8==0)
  const size_t row0 = (size_t)(wg & 15) * 128;   // gridDim.x == 16 always
  const size_t col0 = (size_t)(wg >> 4) * 128;
  floatx4 acc[4][4] = {};
  const bf16*  aSrc = A  + (row0 + (tid >> 2)) * (size_t)K + (tid & 3) * 8;
  const float* bSrc = Bt + (col0 + (tid >> 3)) * (size_t)K + (tid & 7) * 4;
  char* lAb = (char*)&lA[0];

  for (int k0 = 0; k0 < K; k0 += 32) {
    __syncthreads();
#pragma unroll
    for (int s = 0; s < 2; ++s)   // A tile: 128x32 bf16 via lds-DMA, 2 shots
      load_lds16(aSrc + (size_t)s * 64 * K + k0, lAb + s * 4096 + tid * 16);
#pragma unroll
    for (int s = 0; s < 4; ++s) { // B tile: 128x32 fp32 -> bf16, 4 shots
      float4 v = *(const float4*)(bSrc + (size_t)s * 32 * K + k0);
      bf16x4 u = { (bf16)v.x, (bf16)v.y, (bf16)v.z, (bf16)v.w };
      *(bf16x4*)&lB[(s * 32 + (tid >> 3)) * 32 + (tid & 7) * 4] = u;
    }
    __syncthreads();
    bf16x8 af[4], bfv[4];
#pragma unroll
    for (int i = 0; i < 4; ++i)
      af[i] = *(const bf16x8*)&lA[(wm + i * 16 + (lane & 15)) * 32 + (lane >> 4) * 8];
#pragma unroll
    for (int j = 0; j < 4; ++j)
      bfv[j] = *(const bf16x8*)&lB[(wn + j * 16 + (lane & 15)) * 32 + (lane >> 4) * 8];
#pragma unroll
    for (int i = 0; i < 4; ++i)
#pragma unroll
      for (int j = 0; j < 4; ++j)
        acc[i][j] = __builtin_amdgcn_mfma_f32_16x16x32_bf16(af[i], bfv[j], acc[i][j], 0, 0, 0);
  }
#pragma unroll
  for (int i = 0; i < 4; ++i)
#pragma unroll
    for (int j = 0; j < 4; ++j)
#pragma unroll
      for (int r = 0; r < 4; ++r) {
        const size_t row = row0 + wm + i * 16 + (lane >> 4) * 4 + r;
        const size_t col = col0 + wn + j * 16 + (lane & 15);
        C[row * (size_t)N + col] = acc[i][j][r] + bias[col];
      }
}

// ---------------------------------------------------------------------------
// GEMM variant: B already bf16 -> both operands via lds-DMA (m97 fast path).
// ---------------------------------------------------------------------------
__global__ __launch_bounds__(256) void k_gemm_bf(
    const bf16* __restrict__ A, const bf16* __restrict__ B,
    const float* __restrict__ bias, float* __restrict__ C,
    int K, int N)
{
  __shared__ bf16 lA[128 * 32];
  __shared__ bf16 lB[128 * 32];
  const int tid = threadIdx.x;
  const int lane = tid & 63;
  const int wm = ((tid >> 6) >> 1) * 64;
  const int wn = ((tid >> 6) & 1) * 64;
  const int nwg = gridDim.x * gridDim.y;
  int wg = blockIdx.y * gridDim.x + blockIdx.x;
  wg = (wg & 7) * (nwg >> 3) + (wg >> 3);
  const size_t row0 = (size_t)(wg & 15) * 128;
  const size_t col0 = (size_t)(wg >> 4) * 128;
  floatx4 acc[4][4] = {};
  const bf16* aSrc = A + (row0 + (tid >> 2)) * (size_t)K + (tid & 3) * 8;
  const bf16* bSrc = B + (col0 + (tid >> 2)) * (size_t)K + (tid & 3) * 8;
  char* lAb = (char*)&lA[0];
  char* lBb = (char*)&lB[0];

  for (int k0 = 0; k0 < K; k0 += 32) {
    __syncthreads();
#pragma unroll
    for (int s = 0; s < 2; ++s) {
      load_lds16(aSrc + (size_t)s * 64 * K + k0, lAb + s * 4096 + tid * 16);
      load_lds16(bSrc + (size_t)s * 64 * K + k0, lBb + s * 4096 + tid * 16);
    }
    __syncthreads();
    bf16x8 af[4], bfv[4];
#pragma unroll
    for (int i = 0; i < 4; ++i)
      af[i] = *(const bf16x8*)&lA[(wm + i * 16 + (lane & 15)) * 32 + (lane >> 4) * 8];
#pragma unroll
    for (int j = 0; j < 4; ++j)
      bfv[j] = *(const bf16x8*)&lB[(wn + j * 16 + (lane & 15)) * 32 + (lane >> 4) * 8];
#pragma unroll
    for (int i = 0; i < 4; ++i)
#pragma unroll
      for (int j = 0; j < 4; ++j)
        acc[i][j] = __builtin_amdgcn_mfma_f32_16x16x32_bf16(af[i], bfv[j], acc[i][j], 0, 0, 0);
  }
#pragma unroll
  for (int i = 0; i < 4; ++i)
#pragma unroll
    for (int j = 0; j < 4; ++j)
#pragma unroll
      for (int r = 0; r < 4; ++r) {
        const size_t row = row0 + wm + i * 16 + (lane >> 4) * 4 + r;
        const size_t col = col0 + wn + j * 16 + (lane & 15);
        C[row * (size_t)N + col] = acc[i][j][r] + bias[col];
      }
}

// ---------------------------------------------------------------------------
// Fused 2-layer persistent LSTM scan, 1-step software pipeline across layers.
// 256 blocks: bid 0..127 = layer 0 (owns 8 cols, Whh0 in LDS, pre from GEMM);
// bid 128..255 = layer 1 (owns 8 cols, Whh1 + Wih1 in LDS; computes its pre
// in-kernel from h0(t)).  Layer 1 step t waits flags0 >= t+1 and flags1 >= t.
// Layer 0 never waits on layer 1 -> graceful degradation to sequential if
// co-residency fails; bounded spin escapes any pathological stall.
// Weight rows interleaved r = n_local*4 + gate, XOR-swizzled in LDS; C/D
// layout of mfma(W, h) puts the 4 gate pre-acts of one (batch,col) in one
// lane. h exchange: sc0/sc1 write-through + flag post after vmcnt drain.
// ---------------------------------------------------------------------------
__device__ __forceinline__ void stage_w(const bf16* __restrict__ w, int n0,
                                        char* ldsbase, int tid) {
#pragma unroll
  for (int it = 0; it < 16; ++it) {
    const int idx  = it * 256 + tid;           // 16B-chunk id, 0..4095
    const int r    = idx >> 7;                 // lds row 0..31
    const int c16  = idx & 127;                // 16B chunk within row
    const int grow = (r & 3) * 1024 + n0 + (r >> 2);
    const bf16x8 v = *(const bf16x8*)(w + (size_t)grow * 1024 + c16 * 8);
    int byte = r * 2048 + c16 * 16;
    byte ^= (r & 7) << 4;                      // bank-conflict swizzle
    *(bf16x8*)(ldsbase + byte) = v;
  }
}

__device__ __forceinline__ void gemv_pass(const char* lWb, int abase, int axor,
                                          const bf16* hp, floatx4& acc0, floatx4& acc1) {
#pragma unroll
  for (int g8 = 0; g8 < 4; ++g8) {
    bf16x8 hb[8];
#pragma unroll
    for (int u = 0; u < 8; ++u)                // burst of 8 loads in flight
      hb[u] = *(const bf16x8*)(hp + (g8 * 8 + u) * 32);
#pragma unroll
    for (int u = 0; u < 8; ++u) {
      const bf16x8 a = *(const bf16x8*)(lWb + ((abase + (g8 * 8 + u) * 64) ^ axor));
      if (u & 1) acc1 = __builtin_amdgcn_mfma_f32_16x16x32_bf16(a, hb[u], acc1, 0, 0, 0);
      else       acc0 = __builtin_amdgcn_mfma_f32_16x16x32_bf16(a, hb[u], acc0, 0, 0, 0);
    }
  }
}

__device__ __forceinline__ void poll128(const unsigned* flags, unsigned tgt) {
  const int lane = threadIdx.x & 63;
  const unsigned* p = flags + 2 * lane;        // 128 flags, 2/lane
  int spins = 0;
  for (;;) {
    uintx2 f = ld_coh_u32x2(p);
    if (__all(f.x >= tgt && f.y >= tgt)) break;
    if (++spins > 20000) break;                // ~8 ms escape: fail, don't hang
    __builtin_amdgcn_s_sleep(1);
  }
  asm volatile("" ::: "memory");
}

__device__ __forceinline__ void poll256(const unsigned* flags, unsigned tgt0, unsigned tgt1) {
  const int lane = threadIdx.x & 63;
  const unsigned tgt = (lane < 32) ? tgt0 : tgt1;   // lanes 0-31: layer0 flags
  const unsigned* p = flags + 4 * lane;        // 256 flags, 4/lane
  int spins = 0;
  for (;;) {
    uintx4 f = ld_coh_u32x4(p);
    if (__all(f.x >= tgt && f.y >= tgt && f.z >= tgt && f.w >= tgt)) break;
    if (++spins > 20000) break;
    __builtin_amdgcn_s_sleep(1);
  }
  asm volatile("" ::: "memory");
}

__global__ __launch_bounds__(256, 1) void k_lstm_fused(
    bf16* __restrict__ hs0, bf16* __restrict__ hs1,
    const float* __restrict__ pre0, const float* __restrict__ bs1,
    const bf16* __restrict__ whh0, const bf16* __restrict__ whh1,
    const bf16* __restrict__ wih1, unsigned* __restrict__ flags)
{
  __shared__ bf16 lW[2][32 * 1024];            // 128 KB (layer0 uses [0] only)
  __shared__ bf16 hstage[32][8];               // h slice gather (512 B)
  const int tid  = threadIdx.x;
  const int lane = tid & 63;
  const int wave = tid >> 6;
  const bool l1  = blockIdx.x >= 128;
  const int blk  = l1 ? (int)blockIdx.x - 128 : (int)blockIdx.x;
  const int n0   = blk * 8;                    // owned hidden cols
  const int tn   = wave >> 1, tb = wave & 1;

  stage_w(l1 ? whh1 : whh0, n0, (char*)&lW[0][0], tid);
  if (l1) stage_w(wih1, n0, (char*)&lW[1][0], tid);
  __syncthreads();

  const int arow  = tn * 16 + (lane & 15);
  const int axor  = (arow & 7) << 4;
  const int abase = arow * 2048 + (lane >> 4) * 16;
  const int brow  = tb * 16 + (lane & 15);     // batch row (B-frag & owner)
  const int cown  = tn * 4 + (lane >> 4);      // owned col within block
  const char* lWhh = (const char*)&lW[0][0];
  const char* lWih = (const char*)&lW[1][0];

  float b0g = 0.f, b1g = 0.f, b2g = 0.f, b3g = 0.f;
  if (l1) {
    b0g = bs1[0 * 1024 + n0 + cown];
    b1g = bs1[1 * 1024 + n0 + cown];
    b2g = bs1[2 * 1024 + n0 + cown];
    b3g = bs1[3 * 1024 + n0 + cown];
  }

  bf16* hw = l1 ? hs1 : hs0;
  bf16* hwrow = hw + (size_t)tid * 65536 + n0;                 // tid<32 store base
  const bf16* hr_own = hw  + (size_t)brow * 65536 + (lane >> 4) * 8;
  const bf16* hr_h0  = hs0 + (size_t)brow * 65536 + (lane >> 4) * 8;
  const float* preb  = pre0 + (size_t)brow * 64 * 4096 + (n0 + cown);
  unsigned* myflag = flags + (l1 ? 128 : 0) + blk;

  float cstate = 0.f;
#pragma unroll 1
  for (int t = 0; t < 64; ++t) {
    float g0, g1, g2, g3;
    floatx4 acc0 = {}, acc1 = {};
    if (!l1) {
      const float* pp = preb + (size_t)t * 4096;   // issued before poll
      g0 = pp[0]; g1 = pp[1024]; g2 = pp[2048]; g3 = pp[3072];
      if (t > 0) {
        if (wave == 0) poll128(flags, (unsigned)t);
        __syncthreads();                            // release waves 1-3
        gemv_pass(lWhh, abase, axor, hr_own + (size_t)(t - 1) * 1024, acc0, acc1);
      }
      g0 += acc0[0] + acc1[0]; g1 += acc0[1] + acc1[1];
      g2 += acc0[2] + acc1[2]; g3 += acc0[3] + acc1[3];
    } else {
      if (wave == 0) poll256(flags, (unsigned)(t + 1), (unsigned)t);
      __syncthreads();
      gemv_pass(lWih, abase, axor, hr_h0 + (size_t)t * 1024, acc0, acc1);
      if (t > 0)
        gemv_pass(lWhh, abase, axor, hr_own + (size_t)(t - 1) * 1024, acc0, acc1);
      g0 = b0g + acc0[0] + acc1[0]; g1 = b1g + acc0[1] + acc1[1];
      g2 = b2g + acc0[2] + acc1[2]; g3 = b3g + acc0[3] + acc1[3];
    }
    const float iv = sigm(g0), fv = sigm(g1), gv = tanh_f(g2), ov = sigm(g3);
    cstate = fv * cstate + iv * gv;
    hstage[brow][cown] = (bf16)(ov * tanh_f(cstate));
    __syncthreads();                              // hstage complete
    if (tid < 32) {                               // wave 0: store, drain, post
      const uintx4 hv = *(const uintx4*)&hstage[tid][0];
      st_coh_u128(hwrow + (size_t)t * 1024, hv);
      asm volatile("s_waitcnt vmcnt(0)" ::: "memory");
      if (tid == 0) st_coh_u32(myflag, (unsigned)(t + 1));
    }
    // waves 1-3 wait at next iteration's post-poll barrier; hstage not
    // rewritten until wave 0 joins it -> no extra barrier needed here.
  }
}

// ---------------------------------------------------------------------------
extern "C" void kernel_launch(void* const* d_in, const int* in_sizes, int n_in,
                              void* d_out, int out_size, void* d_ws, size_t ws_size,
                              hipStream_t stream)
{
  const float* image = (const float*)d_in[0];
  const int*   caps  = (const int*)d_in[1];
  const float* linW  = (const float*)d_in[2];
  const float* linb  = (const float*)d_in[3];
  const float* gamma = (const float*)d_in[4];
  const float* beta  = (const float*)d_in[5];
  const float* emb   = (const float*)d_in[6];
  const float* Wih0  = (const float*)d_in[7];
  const float* Whh0  = (const float*)d_in[8];
  const float* bih0  = (const float*)d_in[9];
  const float* bhh0  = (const float*)d_in[10];
  const float* Wih1  = (const float*)d_in[11];
  const float* Whh1  = (const float*)d_in[12];
  const float* bih1  = (const float*)d_in[13];
  const float* bhh1  = (const float*)d_in[14];
  const float* fcW   = (const float*)d_in[15];
  const float* fcb   = (const float*)d_in[16];
  float* out = (float*)d_out;

  char* ws = (char*)d_ws;
  size_t off = 0;
  auto alloc = [&](size_t bytes) {
    char* p = ws + off;
    off += (bytes + 255) & ~(size_t)255;
    return p;
  };
  bf16*  whh0b = (bf16*)alloc(4096ull * 1024 * 2);
  bf16*  whh1b = (bf16*)alloc(4096ull * 1024 * 2);
  bf16*  wih1b = (bf16*)alloc(4096ull * 1024 * 2);
  bf16*  xsb   = (bf16*)alloc(2048ull * 512 * 2);
  bf16*  hs0b  = (bf16*)alloc(2048ull * 1024 * 2);
  bf16*  hs1b  = (bf16*)alloc(2048ull * 1024 * 2);
  float* pre   = (float*)alloc(2048ull * 4096 * 4);
  float* bsum0 = (float*)alloc(4096 * 4);
  float* bsum1 = (float*)alloc(4096 * 4);
  unsigned* flg = (unsigned*)alloc(1024);          // 2 layers x 128 flags
  // base ~69 MB; fcwb (+62.5 MB) only if workspace clearly allows
  const bool big = ws_size >= ((size_t)136 << 20);
  bf16* fcwb = big ? (bf16*)alloc(32000ull * 1024 * 2) : (bf16*)0;

  k_zero<<<1, 256, 0, stream>>>(flg);
  k_cvt<<<4096, 256, 0, stream>>>(Whh0, whh0b, 4096 * 1024 / 4);
  k_cvt<<<4096, 256, 0, stream>>>(Whh1, whh1b, 4096 * 1024 / 4);
  k_cvt<<<4096, 256, 0, stream>>>(Wih1, wih1b, 4096 * 1024 / 4);
  if (big) k_cvt<<<32000, 256, 0, stream>>>(fcW, fcwb, 32000 * 1024 / 4);
  k_bias_sum<<<16, 256, 0, stream>>>(bih0, bhh0, bsum0, 4096);
  k_bias_sum<<<16, 256, 0, stream>>>(bih1, bhh1, bsum1, 4096);
  k_linbn<<<512, 256, 0, stream>>>(image, linW, linb, gamma, beta, xsb);
  k_embed<<<2016, 128, 0, stream>>>(caps, emb, xsb);

  // layer-0 pre (K=512), then both layers' scans fused & pipelined
  k_gemm<<<dim3(16, 32), 256, 0, stream>>>(xsb, Wih0, bsum0, pre, 512, 4096);
  k_lstm_fused<<<256, 256, 0, stream>>>(hs0b, hs1b, pre, bsum1,
                                        whh0b, whh1b, wih1b, flg);
  // vocab projection
  if (big)
    k_gemm_bf<<<dim3(16, 250), 256, 0, stream>>>(hs1b, fcwb, fcb, out, 1024, 32000);
  else
    k_gemm<<<dim3(16, 250), 256, 0, stream>>>(hs1b, fcW, fcb, out, 1024, 32000);

  (void)in_sizes; (void)n_in; (void)out_size; (void)ws_size;
}